// Round 4
// baseline (113.268 us; speedup 1.0000x reference)
//
#include <hip/hip_runtime.h>

// B=32768, K=64, D=64, GAIN=1.0
#define LOG_2PI 1.8378770664093453f
#define LOG2E   1.4426950408889634f

typedef __attribute__((ext_vector_type(8))) short  short8;   // 8 x bf16
typedef __attribute__((ext_vector_type(4))) float  float4_;

__device__ __forceinline__ unsigned short f2bf(float f) {
  unsigned u = __builtin_bit_cast(unsigned, f);
  u += 0x7fffu + ((u >> 16) & 1u);   // RNE
  return (unsigned short)(u >> 16);
}
__device__ __forceinline__ float bf2f(unsigned short h) {
  unsigned u = ((unsigned)h) << 16;
  return __builtin_bit_cast(float, u);
}
template <int CTRL>
__device__ __forceinline__ float dpp_add(float v) {
  int t = __builtin_amdgcn_mov_dpp(__builtin_bit_cast(int, v), CTRL, 0xf, 0xf, true);
  return v + __builtin_bit_cast(float, t);
}
__device__ __forceinline__ void async16(const void* g, void* l) {
  __builtin_amdgcn_global_load_lds((const __attribute__((address_space(1))) unsigned int*)g,
                                   (__attribute__((address_space(3))) unsigned int*)l, 16, 0, 0);
}

// ---------------------------------------------------------------------------
// Setup: one block per component k.
//  W image per comp (4608 shorts = 9216 B): row n: shorts [0,64) = bf16
//  W'[n][:] = -0.5*log2e*M[n][:]; row n bytes [128,132) = fp32 c'_n =
//  log2e*c_n; row 0 bytes [132,136) = fp32 beta' = log2e*(beta+90).
//  (log2e folded in so main's epilogue uses exp2 directly.)
// ---------------------------------------------------------------------------
__global__ __launch_bounds__(256) void gmm_setup(
    const float* __restrict__ means_raw, const float* __restrict__ scale_raw,
    const float* __restrict__ weights_raw, unsigned short* __restrict__ Wf)
{
  const int k = blockIdx.x;
  const int t = threadIdx.x;
  const int lane = t & 63;
  const int wv = t >> 6;
  const int q = lane >> 4;
  const int jj = lane & 15;

  __shared__ float Plt[64][68];   // Plt[m][i] = L[i][m] for i>m, else 0
  __shared__ float Vt[64][68];    // Vt[c][m]  = Linv[m][c]
  __shared__ __align__(16) unsigned short Vb[64][72];  // bf16 Vt image
  __shared__ float dg[64], rdg[64], mu_s[64], y_s[64];

  {  // phase 1
    const int i = t >> 2;
    const int c0 = (t & 3) * 16;
    float4_ v4[4];
    const float4_* src = (const float4_*)(scale_raw + (size_t)k * 4096 + i * 64 + c0);
    v4[0] = src[0]; v4[1] = src[1]; v4[2] = src[2]; v4[3] = src[3];
#pragma unroll
    for (int e = 0; e < 16; ++e) {
      const int c = c0 + e;
      const float val = ((const float*)v4)[e] * (1.0f / 512.0f);
      Plt[c][i] = (c < i) ? val : 0.0f;
      if (c == i) { dg[i] = val; rdg[i] = __expf(-val); }
    }
  }
  if (t < 64) mu_s[t] = means_raw[k * 64 + t] * (1.0f / 64.0f);
  __syncthreads();

  // phase 2: forward substitution (col j = wv*16+jj, rows [16q,16q+16))
  {
    const int j = wv * 16 + jj;
    float s[16];
#pragma unroll
    for (int i = 0; i < 16; ++i) s[i] = 0.0f;
#pragma unroll
    for (int m = 0; m < 64; ++m) {
      const float rm = rdg[m];
      float vcand = (m == j) ? rm : -s[m & 15] * rm;
      const float v = __shfl(vcand, (m >> 4) * 16 + jj, 64);
      if (q == (m >> 4)) {
        Vt[j][m] = v;
        Vb[j][m] = f2bf(v);
      }
      const float4_* prow = (const float4_*)&Plt[m][16 * q];
      const float4_ p0 = prow[0], p1 = prow[1], p2 = prow[2], p3 = prow[3];
      s[0]  += p0[0] * v; s[1]  += p0[1] * v; s[2]  += p0[2] * v; s[3]  += p0[3] * v;
      s[4]  += p1[0] * v; s[5]  += p1[1] * v; s[6]  += p1[2] * v; s[7]  += p1[3] * v;
      s[8]  += p2[0] * v; s[9]  += p2[1] * v; s[10] += p2[2] * v; s[11] += p2[3] * v;
      s[12] += p3[0] * v; s[13] += p3[1] * v; s[14] += p3[2] * v; s[15] += p3[3] * v;
    }
  }
  __syncthreads();

  // phase 3a: M = V^T V via MFMA; W' = -0.5*log2e*M
  {
    unsigned short* Wk = Wf + (size_t)k * 4608;
    const short8 a0 = *(const short8*)&Vb[16 * wv + jj][8 * q];
    const short8 a1 = *(const short8*)&Vb[16 * wv + jj][8 * q + 32];
#pragma unroll
    for (int t4 = 0; t4 < 4; ++t4) {
      const short8 b0 = *(const short8*)&Vb[jj + 16 * t4][8 * q];
      const short8 b1 = *(const short8*)&Vb[jj + 16 * t4][8 * q + 32];
      float4_ f = {0.f, 0.f, 0.f, 0.f};
      f = __builtin_amdgcn_mfma_f32_16x16x32_bf16(a0, b0, f, 0, 0, 0);
      f = __builtin_amdgcn_mfma_f32_16x16x32_bf16(a1, b1, f, 0, 0, 0);
#pragma unroll
      for (int r = 0; r < 4; ++r)
        Wk[(16 * wv + 4 * q + r) * 72 + jj + 16 * t4] = f2bf(-0.5f * LOG2E * f[r]);
    }
  }
  if (wv == 0) {  // y = V*mu
    float acc = 0.0f;
    for (int j2 = 0; j2 < 64; ++j2) acc += Vt[j2][lane] * mu_s[j2];
    y_s[lane] = acc;
  }
  __syncthreads();

  // tail: c' = log2e * V^T y, beta' = log2e*(beta+90)
  if (t < 64) {
    const int i = t;
    float ci = 0.0f;
#pragma unroll
    for (int m4 = 0; m4 < 16; ++m4) {
      const float4_ a4 = *(const float4_*)&Vt[i][4 * m4];
      const float4_ b4 = *(const float4_*)&y_s[4 * m4];
      ci += a4[0] * b4[0] + a4[1] * b4[1] + a4[2] * b4[2] + a4[3] * b4[3];
    }
    char* Wk = (char*)(Wf + (size_t)k * 4608);
    *(float*)(Wk + i * 144 + 128) = LOG2E * ci;
    float rq  = ci * mu_s[i];
    float dgv = dg[i];
    const float wr = weights_raw[i] * 0.125f;
    float mx = wr;
#pragma unroll
    for (int d = 1; d < 64; d <<= 1) mx = fmaxf(mx, __shfl_xor(mx, d, 64));
    float se = __expf(wr - mx);
#pragma unroll
    for (int d = 1; d < 64; d <<= 1) {
      se  += __shfl_xor(se, d, 64);
      rq  += __shfl_xor(rq, d, 64);
      dgv += __shfl_xor(dgv, d, 64);
    }
    if (i == 0) {
      const float wrk  = weights_raw[k] * 0.125f;
      const float logw = wrk - mx - __logf(se);
      const float beta = -0.5f * rq - 32.0f * LOG_2PI - dgv + logw;
      *(float*)(Wk + 132) = LOG2E * (beta + 90.0f);
    }
  }
}

// ---------------------------------------------------------------------------
// Main: 512 blocks x 256 threads, 2 blocks/CU. kh = &3 (16 comps),
// rt = >>2 (256 rows). Wave owns 64 rows (mt=4) -> each 8-KB W read from LDS
// feeds 32 MFMAs (halves device LDS-read traffic vs mt=2, the R3 bottleneck).
// KG=2 double-buffered global_load_lds staging. Epilogue uses exp2
// (log2e pre-folded into W/c/beta by setup).
// ---------------------------------------------------------------------------
__global__ __launch_bounds__(256, 2) void gmm_main(
    const float* __restrict__ x, const unsigned short* __restrict__ Wf,
    unsigned short* __restrict__ ph)
{
  __shared__ __align__(16) unsigned short Wlds[2][2][4608];

  const int t = threadIdx.x;
  const int lane = t & 63;
  const int wv = t >> 6;
  const int q = lane >> 4;
  const int lr = lane & 15;
  const int kh = blockIdx.x & 3;
  const int rt = blockIdx.x >> 2;
  const int rowBase = rt * 256 + wv * 64;
  const int kbase = kh * 16;

  // A fragments: A[m=lr][kdim=8q+32ks+j], 4 m-tiles
  short8 a[4][2];
#pragma unroll
  for (int mt = 0; mt < 4; ++mt)
#pragma unroll
    for (int ks = 0; ks < 2; ++ks) {
      const float4_* xv = (const float4_*)(x + (size_t)(rowBase + mt * 16 + lr) * 64 + ks * 32 + q * 8);
      const float4_ lo = xv[0], hi = xv[1];
      short8 v;
      v[0] = f2bf(lo[0]); v[1] = f2bf(lo[1]); v[2] = f2bf(lo[2]); v[3] = f2bf(lo[3]);
      v[4] = f2bf(hi[0]); v[5] = f2bf(hi[1]); v[6] = f2bf(hi[2]); v[7] = f2bf(hi[3]);
      a[mt][ks] = v;
    }

  // fp32 x in C layout: xc[mt][t4][r] = x[rowBase+mt*16+4q+r][lr+16*t4]
  float xc[4][4][4];
#pragma unroll
  for (int mt = 0; mt < 4; ++mt)
#pragma unroll
    for (int r = 0; r < 4; ++r) {
      const float* xp = x + (size_t)(rowBase + mt * 16 + q * 4 + r) * 64 + lr;
#pragma unroll
      for (int t4 = 0; t4 < 4; ++t4) xc[mt][t4][r] = xp[16 * t4];
    }

  float sacc[4][4] = {{0,0,0,0},{0,0,0,0},{0,0,0,0},{0,0,0,0}};

#define STAGE(g, slot)                                                          \
  {                                                                             \
    const unsigned short* src = Wf + (size_t)(kbase + 2 * (g)) * 4608 + t * 8;  \
    unsigned short* dst = &Wlds[slot][0][0] + t * 8;                            \
    async16(src,         dst);                                                  \
    async16(src + 2048,  dst + 2048);                                           \
    async16(src + 4096,  dst + 4096);                                           \
    async16(src + 6144,  dst + 6144);                                           \
    if (t < 128) async16(src + 8192, dst + 8192);                               \
  }

  STAGE(0, 0)
  __syncthreads();

  for (int g = 0; g < 8; ++g) {
    const int cur = g & 1;
    if (g < 7) STAGE(g + 1, cur ^ 1)
#pragma unroll
    for (int kk = 0; kk < 2; ++kk) {
      const unsigned short* wb = &Wlds[cur][kk][0];
      float cc[4];
#pragma unroll
      for (int t4 = 0; t4 < 4; ++t4)
        cc[t4] = *(const float*)(wb + (lr + 16 * t4) * 72 + 64);
      const float bk = *(const float*)(wb + 66);

      short8 b[2][4];
#pragma unroll
      for (int t4 = 0; t4 < 4; ++t4)
#pragma unroll
        for (int ks = 0; ks < 2; ++ks)
          b[ks][t4] = *(const short8*)(wb + (lr + 16 * t4) * 72 + 8 * q + 32 * ks);

#pragma unroll
      for (int mh = 0; mh < 2; ++mh) {
        float4_ f[2][4];
#pragma unroll
        for (int mi = 0; mi < 2; ++mi)
#pragma unroll
          for (int t4 = 0; t4 < 4; ++t4) {
            const float cv = cc[t4];
            float4_ acc = {cv, cv, cv, cv};
            acc = __builtin_amdgcn_mfma_f32_16x16x32_bf16(a[2 * mh + mi][0], b[0][t4], acc, 0, 0, 0);
            acc = __builtin_amdgcn_mfma_f32_16x16x32_bf16(a[2 * mh + mi][1], b[1][t4], acc, 0, 0, 0);
            f[mi][t4] = acc;
          }
#pragma unroll
        for (int mi = 0; mi < 2; ++mi) {
          const int mt = 2 * mh + mi;
#pragma unroll
          for (int r = 0; r < 4; ++r) {
            float sdot = xc[mt][0][r] * f[mi][0][r] + xc[mt][1][r] * f[mi][1][r]
                       + xc[mt][2][r] * f[mi][2][r] + xc[mt][3][r] * f[mi][3][r];
            sdot = dpp_add<0x121>(sdot);  // row_ror:1
            sdot = dpp_add<0x122>(sdot);  // row_ror:2
            sdot = dpp_add<0x124>(sdot);  // row_ror:4
            sdot = dpp_add<0x128>(sdot);  // row_ror:8
            sacc[mt][r] += exp2f(sdot + bk);
          }
        }
      }
    }
    __syncthreads();
  }
#undef STAGE

  if (lr == 0) {
#pragma unroll
    for (int mt = 0; mt < 4; ++mt)
#pragma unroll
      for (int r = 0; r < 4; ++r)
        ph[(size_t)kh * 32768 + rowBase + mt * 16 + q * 4 + r] = f2bf(sacc[mt][r]);
  }
}

// ---------------------------------------------------------------------------
__global__ __launch_bounds__(256) void gmm_final(const unsigned short* __restrict__ ph,
                                                 float* __restrict__ out)
{
  const int t = threadIdx.x;
  const int r0 = blockIdx.x * 512 + t;
  float v = 0.0f;
#pragma unroll
  for (int h = 0; h < 2; ++h) {
    const int row = r0 + 256 * h;
    const float s = bf2f(ph[row]) + bf2f(ph[32768 + row])
                  + bf2f(ph[65536 + row]) + bf2f(ph[98304 + row]);
    v += __logf(s) - 90.0f;
  }
#pragma unroll
  for (int d = 1; d < 64; d <<= 1) v += __shfl_xor(v, d, 64);
  __shared__ float s4[4];
  if ((t & 63) == 0) s4[t >> 6] = v;
  __syncthreads();
  if (t == 0)
    atomicAdd(out, -(s4[0] + s4[1] + s4[2] + s4[3]) * (1.0f / 32768.0f));
}

extern "C" void kernel_launch(void* const* d_in, const int* in_sizes, int n_in,
                              void* d_out, int out_size, void* d_ws, size_t ws_size,
                              hipStream_t stream)
{
  const float* x           = (const float*)d_in[0];  // [32768,64]
  const float* means_raw   = (const float*)d_in[1];  // [64,64]
  const float* scale_raw   = (const float*)d_in[2];  // [64,64,64]
  const float* weights_raw = (const float*)d_in[3];  // [64]
  float* out = (float*)d_out;

  char* ws = (char*)d_ws;
  unsigned short* Wf = (unsigned short*)ws;            // 64*4608*2 = 589824 B
  unsigned short* ph = (unsigned short*)(ws + 589824); // 4*32768*2 = 262144 B

  hipMemsetAsync(out, 0, sizeof(float), stream);
  gmm_setup<<<64, 256, 0, stream>>>(means_raw, scale_raw, weights_raw, Wf);
  gmm_main<<<512, 256, 0, stream>>>(x, Wf, ph);
  gmm_final<<<64, 256, 0, stream>>>(ph, out);
}